// Round 1
// 788.425 us; speedup vs baseline: 2.2516x; 2.2516x over previous
//
#include <hip/hip_runtime.h>
#include <cmath>

// Problem constants
#define BB 2
#define TT 2048
#define CC 1024
#define HH 16
#define DD 64

typedef unsigned short u16;
typedef __attribute__((ext_vector_type(8))) short bf16x8;   // 8 bf16 = 4 VGPRs
typedef __attribute__((ext_vector_type(4))) float f32x4;

__device__ __forceinline__ u16 f2bf(float f) {
    union { float f; unsigned u; } v; v.f = f;
    return (u16)((v.u + 0x7fff + ((v.u >> 16) & 1)) >> 16);   // RNE
}

__device__ __forceinline__ float bf2f(u16 h) {
    union { unsigned u; float f; } v; v.u = ((unsigned)h) << 16;
    return v.f;
}

__device__ __forceinline__ float gelu_exact(float v) {
    return 0.5f * v * (1.0f + erff(v * 0.70710678118654752440f));
}

__device__ __forceinline__ void glds16(const void* g, void* l) {
    __builtin_amdgcn_global_load_lds(
        (const __attribute__((address_space(1))) void*)g,
        (__attribute__((address_space(3))) void*)l, 16, 0, 0);
}

// ---------------------------------------------------------------------------
// Weight convert + transpose: W [K,N] fp32 -> WT [N,K] bf16. 64x64 tiles.
// grid = (N/64, K/64), 256 threads.
// ---------------------------------------------------------------------------
__global__ __launch_bounds__(256) void wcvt_kernel(const float* __restrict__ W,
                                                   u16* __restrict__ WT,
                                                   int K, int N) {
    __shared__ u16 t[64][65];
    const int n0 = blockIdx.x * 64, k0 = blockIdx.y * 64;
    const int tid = threadIdx.x;
    const int c = tid & 63;
#pragma unroll
    for (int it = 0; it < 16; ++it) {
        int r = it * 4 + (tid >> 6);
        t[c][r] = f2bf(W[(size_t)(k0 + r) * N + n0 + c]);
    }
    __syncthreads();
#pragma unroll
    for (int it = 0; it < 16; ++it) {
        int r = it * 4 + (tid >> 6);
        WT[(size_t)(n0 + r) * K + k0 + c] = t[r][c];
    }
}

// ---------------------------------------------------------------------------
// LayerNorm: fp32 in, bf16 out. One block per row of C=1024.
// ---------------------------------------------------------------------------
__global__ __launch_bounds__(256) void ln_kernel(const float* __restrict__ x,
                                                 const float* __restrict__ w,
                                                 const float* __restrict__ b,
                                                 u16* __restrict__ out) {
    const int row = blockIdx.x;
    const int tid = threadIdx.x;
    const float* xr = x + (size_t)row * CC;
    u16* orow = out + (size_t)row * CC;

    __shared__ float red[256];

    float v[4];
#pragma unroll
    for (int i = 0; i < 4; ++i) v[i] = xr[tid + i * 256];

    red[tid] = v[0] + v[1] + v[2] + v[3];
    __syncthreads();
    for (int off = 128; off > 0; off >>= 1) {
        if (tid < off) red[tid] += red[tid + off];
        __syncthreads();
    }
    const float mean = red[0] * (1.0f / CC);
    __syncthreads();

    float d[4], sq = 0.f;
#pragma unroll
    for (int i = 0; i < 4; ++i) { d[i] = v[i] - mean; sq += d[i] * d[i]; }
    red[tid] = sq;
    __syncthreads();
    for (int off = 128; off > 0; off >>= 1) {
        if (tid < off) red[tid] += red[tid + off];
        __syncthreads();
    }
    const float rstd = rsqrtf(red[0] * (1.0f / CC) + 1e-5f);

#pragma unroll
    for (int i = 0; i < 4; ++i) {
        int c = tid + i * 256;
        orow[c] = f2bf(d[i] * rstd * w[c] + b[c]);
    }
}

// ---------------------------------------------------------------------------
// bf16 MFMA GEMM (m97 structure): out[M,N] = epi(A[M,K] @ BT[N,K]^T + bias).
// TK=32, 256 threads = 4 waves at (WM x WN), each wave FI x FJ frags of
// 16x16x32. TM = WM*FI*16, TN = WN*FJ*16. global_load_lds width-16 staging.
// EPI: 0=bias, 1=bias+GELU, 2=bias+residual. OUTBF: 1 = store bf16.
// ---------------------------------------------------------------------------
template <int EPI, int OUTBF, int WM, int WN, int FI, int FJ>
__global__ __launch_bounds__(256) void gemm_mfma(const u16* __restrict__ A,
                                                 const u16* __restrict__ BT,
                                                 const float* __restrict__ bias,
                                                 const float* __restrict__ res,
                                                 void* __restrict__ out,
                                                 int M, int N, int K) {
    constexpr int TM = WM * FI * 16;
    constexpr int TN = WN * FJ * 16;
    __shared__ u16 As[TM * 32];
    __shared__ u16 Bs[TN * 32];

    const int tid = threadIdx.x;
    const int lane = tid & 63;
    const int w = tid >> 6;                 // wave 0..3
    const int wr = w / WN, wc = w % WN;
    const int m16 = lane & 15;
    const int quad = lane >> 4;

    const int bm = blockIdx.y * TM;
    const int bn = blockIdx.x * TN;

    f32x4 acc[FI][FJ] = {};

    for (int k0 = 0; k0 < K; k0 += 32) {
        // stage A tile (TM x 32) and B tile (TN x 32), 16B per lane
#pragma unroll
        for (int it = 0; it < TM / 64; ++it) {
            int cb = w * (TM / 64) * 64 + it * 64;     // wave-uniform chunk base
            int q = cb + lane;
            glds16(&A[(size_t)(bm + (q >> 2)) * K + k0 + (q & 3) * 8], &As[cb * 8]);
        }
#pragma unroll
        for (int it = 0; it < TN / 64; ++it) {
            int cb = w * (TN / 64) * 64 + it * 64;
            int q = cb + lane;
            glds16(&BT[(size_t)(bn + (q >> 2)) * K + k0 + (q & 3) * 8], &Bs[cb * 8]);
        }
        __syncthreads();

        bf16x8 a[FI], b[FJ];
#pragma unroll
        for (int i = 0; i < FI; ++i)
            a[i] = *(const bf16x8*)&As[(wr * FI * 16 + 16 * i + m16) * 32 + quad * 8];
#pragma unroll
        for (int j = 0; j < FJ; ++j)
            b[j] = *(const bf16x8*)&Bs[(wc * FJ * 16 + 16 * j + m16) * 32 + quad * 8];
#pragma unroll
        for (int i = 0; i < FI; ++i)
#pragma unroll
            for (int j = 0; j < FJ; ++j)
                acc[i][j] = __builtin_amdgcn_mfma_f32_16x16x32_bf16(a[i], b[j], acc[i][j], 0, 0, 0);
        __syncthreads();
    }

    // epilogue: C/D layout col=lane&15, row=quad*4+reg
#pragma unroll
    for (int i = 0; i < FI; ++i) {
        const int row = bm + wr * FI * 16 + 16 * i + quad * 4;
#pragma unroll
        for (int j = 0; j < FJ; ++j) {
            const int col = bn + wc * FJ * 16 + 16 * j + m16;
            const float bv = bias[col];
#pragma unroll
            for (int r = 0; r < 4; ++r) {
                float v = acc[i][j][r] + bv;
                if (EPI == 1) v = gelu_exact(v);
                if (EPI == 2) v += res[(size_t)(row + r) * N + col];
                if (OUTBF) ((u16*)out)[(size_t)(row + r) * N + col] = f2bf(v);
                else ((float*)out)[(size_t)(row + r) * N + col] = v;
            }
        }
    }
}

// ---------------------------------------------------------------------------
// MFMA two-pass causal attention.
// Block = (head h, 64-row Q tile tt), both batches. 256 threads = 4 waves,
// wave w owns rows w*16..w*16+15 of the tile.
// S = Qh*Kh + Ql*Kh + Qh*Kl (bf16 hi/lo split -> fp32-grade scores, so the
// softmax stats and attn_mean keep fp32 accuracy). P,V in bf16 for PV MFMA.
// All LDS tiles [64][64] bf16 with XOR swizzle (u16 col ^= (row&7)<<3) so
// ds_read_b128 fragment reads are ~conflict-free.
// ---------------------------------------------------------------------------
__global__ __launch_bounds__(256) void attn_kernel(const float* __restrict__ qkv,
                                                   float* __restrict__ attn_mean,
                                                   u16* __restrict__ attn_out) {
    const int lid = blockIdx.x;
    const int u = lid & 255;
    const int h = u & 15;
    const int ta = u >> 4;
    const int tt = (lid < 256) ? ta : 31 - ta;
    const int t0 = tt * 64;

    const int tid = threadIdx.x;
    const int lane = tid & 63;
    const int w = tid >> 6;                 // wave 0..3
    const int m16 = lane & 15;
    const int quad = lane >> 4;
    const size_t TC3 = 3 * CC;

    __shared__ u16 Qh[2][64][64];   // 16 KB  (hi bf16, pre-scaled by 1/8)
    __shared__ u16 Ql[2][64][64];   // 16 KB  (lo residual bf16)
    __shared__ u16 Kh[64][64];      // 8 KB
    __shared__ u16 Kl[64][64];      // 8 KB
    __shared__ u16 VT[64][64];      // 8 KB   VT[d][s] (V transposed)
    __shared__ u16 Ps[64][64];      // 8 KB   normalized P, bf16

    const int arow = w * 16 + m16;          // A-fragment LDS row
    const int sw = (m16 & 7) << 3;          // read-side swizzle (u16 units)
    const int rbase = w * 16 + quad * 4;    // C/D row base within tile

    // stage 64x64 fp32 tile -> hi/lo bf16 LDS, swizzled. src row stride 3C.
    auto stage_hilo = [&](const float* src, u16 (*Hd)[64], u16 (*Ld)[64], float scale) {
#pragma unroll
        for (int it = 0; it < 4; ++it) {
            int e = tid + it * 256;
            int s = e >> 4, c4 = e & 15;
            float4 v = *reinterpret_cast<const float4*>(src + (size_t)s * TC3 + c4 * 4);
            float fv[4] = {v.x * scale, v.y * scale, v.z * scale, v.w * scale};
            u16 hh[4], ll[4];
#pragma unroll
            for (int i = 0; i < 4; ++i) {
                union { float f; unsigned u; } tbits; tbits.f = fv[i];
                hh[i] = (u16)(tbits.u >> 16);              // truncated hi
                ll[i] = f2bf(fv[i] - bf2f(hh[i]));         // RNE residual
            }
            int col = (c4 * 4) ^ ((s & 7) << 3);
            *reinterpret_cast<ushort4*>(&Hd[s][col]) = make_ushort4(hh[0], hh[1], hh[2], hh[3]);
            *reinterpret_cast<ushort4*>(&Ld[s][col]) = make_ushort4(ll[0], ll[1], ll[2], ll[3]);
        }
    };

    // stage V tile transposed: VT[d][s] bf16, swizzled by d.
    auto stage_vt = [&](const float* src) {
#pragma unroll
        for (int it = 0; it < 4; ++it) {
            int e = tid + it * 256;
            int s = e >> 4, c4 = e & 15;
            float4 v = *reinterpret_cast<const float4*>(src + (size_t)s * TC3 + c4 * 4);
            float fv[4] = {v.x, v.y, v.z, v.w};
#pragma unroll
            for (int i = 0; i < 4; ++i) {
                int d = c4 * 4 + i;
                VT[d][s ^ ((d & 7) << 3)] = f2bf(fv[i]);
            }
        }
    };

    // S tile for batch b into acc (adds into acc; caller zero-inits).
    auto compute_S = [&](int b, f32x4 (&acc)[4], bool diag) {
#pragma unroll
        for (int ks = 0; ks < 2; ++ks) {
            const int acol = (ks * 32 + quad * 8) ^ sw;
            bf16x8 ah = *(const bf16x8*)&Qh[b][arow][acol];
            bf16x8 al = *(const bf16x8*)&Ql[b][arow][acol];
#pragma unroll
            for (int j = 0; j < 4; ++j) {
                bf16x8 bh = *(const bf16x8*)&Kh[j * 16 + m16][acol];
                bf16x8 bl = *(const bf16x8*)&Kl[j * 16 + m16][acol];
                acc[j] = __builtin_amdgcn_mfma_f32_16x16x32_bf16(ah, bh, acc[j], 0, 0, 0);
                acc[j] = __builtin_amdgcn_mfma_f32_16x16x32_bf16(al, bh, acc[j], 0, 0, 0);
                acc[j] = __builtin_amdgcn_mfma_f32_16x16x32_bf16(ah, bl, acc[j], 0, 0, 0);
            }
        }
        if (diag) {
#pragma unroll
            for (int j = 0; j < 4; ++j)
#pragma unroll
                for (int r = 0; r < 4; ++r)
                    if (j * 16 + m16 > rbase + r) acc[j][r] = -INFINITY;
        }
    };

    // PV accumulate: O[j] += Ps(strip) @ VT
    auto pv_acc = [&](f32x4 (&O)[4]) {
#pragma unroll
        for (int ks = 0; ks < 2; ++ks) {
            const int ko = (ks * 32 + quad * 8) ^ sw;
            bf16x8 a = *(const bf16x8*)&Ps[arow][ko];
#pragma unroll
            for (int j = 0; j < 4; ++j) {
                bf16x8 bv = *(const bf16x8*)&VT[j * 16 + m16][ko];
                O[j] = __builtin_amdgcn_mfma_f32_16x16x32_bf16(a, bv, O[j], 0, 0, 0);
            }
        }
    };

    // ---- stage Q (both batches), scaled by 1/sqrt(D) ----
    stage_hilo(qkv + (size_t)t0 * TC3 + h * DD, Qh[0], Ql[0], 0.125f);
    stage_hilo(qkv + (size_t)TT * TC3 + (size_t)t0 * TC3 + h * DD, Qh[1], Ql[1], 0.125f);

    // ---- Pass A: online row max m and denom l, entirely in registers ----
    float m_b[2][4], l_b[2][4];
#pragma unroll
    for (int b = 0; b < 2; ++b) {
        float m_r[4] = {-INFINITY, -INFINITY, -INFINITY, -INFINITY};
        float l_r[4] = {0.f, 0.f, 0.f, 0.f};
        const float* kbase = qkv + (size_t)b * TT * TC3 + CC + h * DD;
        for (int st = 0; st <= tt; ++st) {
            __syncthreads();
            stage_hilo(kbase + (size_t)st * 64 * TC3, Kh, Kl, 1.0f);
            __syncthreads();
            f32x4 acc[4] = {};
            compute_S(b, acc, st == tt);
#pragma unroll
            for (int r = 0; r < 4; ++r) {
                float t = fmaxf(fmaxf(acc[0][r], acc[1][r]), fmaxf(acc[2][r], acc[3][r]));
                t = fmaxf(t, __shfl_xor(t, 1));
                t = fmaxf(t, __shfl_xor(t, 2));
                t = fmaxf(t, __shfl_xor(t, 4));
                t = fmaxf(t, __shfl_xor(t, 8));
                const float mn = fmaxf(m_r[r], t);
                float sum = __expf(acc[0][r] - mn) + __expf(acc[1][r] - mn) +
                            __expf(acc[2][r] - mn) + __expf(acc[3][r] - mn);
                sum += __shfl_xor(sum, 1);
                sum += __shfl_xor(sum, 2);
                sum += __shfl_xor(sum, 4);
                sum += __shfl_xor(sum, 8);
                l_r[r] = l_r[r] * __expf(m_r[r] - mn) + sum;
                m_r[r] = mn;
            }
        }
#pragma unroll
        for (int r = 0; r < 4; ++r) { m_b[b][r] = m_r[r]; l_b[b][r] = 1.0f / l_r[r]; }
    }

    // ---- Pass B: recompute S, write attn_mean, PV via MFMA ----
    f32x4 O0[4] = {}, O1[4] = {};
    const float* k0base = qkv + CC + h * DD;
    const float* k1base = qkv + (size_t)TT * TC3 + CC + h * DD;
    const float* v0base = qkv + 2 * CC + h * DD;
    const float* v1base = qkv + (size_t)TT * TC3 + 2 * CC + h * DD;

    for (int st = 0; st <= tt; ++st) {
        const int s0 = st * 64;
        const bool diag = (st == tt);
        float P0[4][4], P1[4][4];

        __syncthreads();
        stage_hilo(k0base + (size_t)s0 * TC3, Kh, Kl, 1.0f);
        __syncthreads();
        {
            f32x4 acc[4] = {};
            compute_S(0, acc, diag);
#pragma unroll
            for (int j = 0; j < 4; ++j)
#pragma unroll
                for (int r = 0; r < 4; ++r)
                    P0[j][r] = __expf(acc[j][r] - m_b[0][r]) * l_b[0][r];
        }
        __syncthreads();
        stage_hilo(k1base + (size_t)s0 * TC3, Kh, Kl, 1.0f);
        __syncthreads();
        {
            f32x4 acc[4] = {};
            compute_S(1, acc, diag);
#pragma unroll
            for (int j = 0; j < 4; ++j)
#pragma unroll
                for (int r = 0; r < 4; ++r)
                    P1[j][r] = __expf(acc[j][r] - m_b[1][r]) * l_b[1][r];
        }
        // attn_mean = 0.5*(P0+P1)
#pragma unroll
        for (int r = 0; r < 4; ++r) {
            float* mrow = attn_mean + ((size_t)h * TT + t0 + rbase + r) * TT + s0;
#pragma unroll
            for (int j = 0; j < 4; ++j)
                mrow[j * 16 + m16] = 0.5f * (P0[j][r] + P1[j][r]);
        }
        // Ps <- P0 (bf16, swizzled), VT <- V(b0)
#pragma unroll
        for (int r = 0; r < 4; ++r) {
            const int prow = rbase + r;
            const int psw = (prow & 7) << 3;
#pragma unroll
            for (int j = 0; j < 4; ++j)
                Ps[prow][(j * 16 + m16) ^ psw] = f2bf(P0[j][r]);
        }
        stage_vt(v0base + (size_t)s0 * TC3);
        __syncthreads();
        pv_acc(O0);
        __syncthreads();
        // Ps <- P1, VT <- V(b1)
#pragma unroll
        for (int r = 0; r < 4; ++r) {
            const int prow = rbase + r;
            const int psw = (prow & 7) << 3;
#pragma unroll
            for (int j = 0; j < 4; ++j)
                Ps[prow][(j * 16 + m16) ^ psw] = f2bf(P1[j][r]);
        }
        stage_vt(v1base + (size_t)s0 * TC3);
        __syncthreads();
        pv_acc(O1);
    }

    // ---- epilogue: att_o bf16 ----
#pragma unroll
    for (int r = 0; r < 4; ++r) {
        const int trow = t0 + rbase + r;
#pragma unroll
        for (int j = 0; j < 4; ++j) {
            attn_out[((size_t)0 * TT + trow) * CC + h * DD + j * 16 + m16] = f2bf(O0[j][r]);
            attn_out[((size_t)1 * TT + trow) * CC + h * DD + j * 16 + m16] = f2bf(O1[j][r]);
        }
    }

    // zero upper triangle of attn_mean rows owned by this block
    const int c0 = (tt + 1) * 64;
    const float4 z4 = make_float4(0.f, 0.f, 0.f, 0.f);
    for (int r = 0; r < 64; ++r) {
        float* row = attn_mean + ((size_t)h * TT + t0 + r) * TT;
        for (int c = c0 + tid * 4; c < TT; c += 1024)
            *reinterpret_cast<float4*>(row + c) = z4;
    }
}

// ---------------------------------------------------------------------------
extern "C" void kernel_launch(void* const* d_in, const int* in_sizes, int n_in,
                              void* d_out, int out_size, void* d_ws, size_t ws_size,
                              hipStream_t stream) {
    const float* x      = (const float*)d_in[0];
    const float* ln1_w  = (const float*)d_in[1];
    const float* ln1_b  = (const float*)d_in[2];
    const float* w_qkv  = (const float*)d_in[3];
    const float* b_qkv  = (const float*)d_in[4];
    const float* w_proj = (const float*)d_in[5];
    const float* b_proj = (const float*)d_in[6];
    const float* ln2_w  = (const float*)d_in[7];
    const float* ln2_b  = (const float*)d_in[8];
    const float* w_fc   = (const float*)d_in[9];
    const float* b_fc   = (const float*)d_in[10];
    const float* w_fc2  = (const float*)d_in[11];
    const float* b_fc2  = (const float*)d_in[12];

    float* out_x    = (float*)d_out;
    float* out_attn = out_x + (size_t)BB * TT * CC;

    char* wp = (char*)d_ws;
    u16* wT_qkv = (u16*)wp;  wp += (size_t)3072 * 1024 * 2;
    u16* wT_proj = (u16*)wp; wp += (size_t)1024 * 1024 * 2;
    u16* wT_fc  = (u16*)wp;  wp += (size_t)4096 * 1024 * 2;
    u16* wT_fc2 = (u16*)wp;  wp += (size_t)1024 * 4096 * 2;
    u16* h_ln   = (u16*)wp;  wp += (size_t)4096 * 1024 * 2;
    u16* att_o  = (u16*)wp;  wp += (size_t)4096 * 1024 * 2;
    u16* h2     = (u16*)wp;  wp += (size_t)4096 * 4096 * 2;
    float* qkv  = (float*)wp; wp += (size_t)4096 * 3072 * 4;
    float* x1   = (float*)wp; wp += (size_t)4096 * 1024 * 4;

    const int M = BB * TT;   // 4096

    // weight convert+transpose (bf16, [N,K])
    wcvt_kernel<<<dim3(3072 / 64, 1024 / 64), 256, 0, stream>>>(w_qkv, wT_qkv, 1024, 3072);
    wcvt_kernel<<<dim3(1024 / 64, 1024 / 64), 256, 0, stream>>>(w_proj, wT_proj, 1024, 1024);
    wcvt_kernel<<<dim3(4096 / 64, 1024 / 64), 256, 0, stream>>>(w_fc, wT_fc, 1024, 4096);
    wcvt_kernel<<<dim3(1024 / 64, 4096 / 64), 256, 0, stream>>>(w_fc2, wT_fc2, 4096, 1024);

    // 1. LN1 -> bf16
    ln_kernel<<<M, 256, 0, stream>>>(x, ln1_w, ln1_b, h_ln);
    // 2. qkv = h_ln @ w_qkv + b_qkv  [4096,3072] fp32  (128x128 tiles)
    gemm_mfma<0, 0, 2, 2, 4, 4><<<dim3(3072 / 128, M / 128), 256, 0, stream>>>(
        h_ln, wT_qkv, b_qkv, nullptr, qkv, M, 3072, 1024);
    // 3. attention (fp32 in, bf16 att_o out) — MFMA two-pass
    attn_kernel<<<512, 256, 0, stream>>>(qkv, out_attn, att_o);
    // 4. x1 = x + att_o @ w_proj + b_proj  [4096,1024] fp32  (128x64 tiles)
    gemm_mfma<2, 0, 4, 1, 2, 4><<<dim3(1024 / 64, M / 128), 256, 0, stream>>>(
        att_o, wT_proj, b_proj, x, x1, M, 1024, 1024);
    // 5. LN2 -> bf16
    ln_kernel<<<M, 256, 0, stream>>>(x1, ln2_w, ln2_b, h_ln);
    // 6. h2 = gelu(h_ln @ w_fc + b_fc)  [4096,4096] bf16  (128x128 tiles)
    gemm_mfma<1, 1, 2, 2, 4, 4><<<dim3(4096 / 128, M / 128), 256, 0, stream>>>(
        h_ln, wT_fc, b_fc, nullptr, h2, M, 4096, 1024);
    // 7. out_x = x1 + h2 @ w_fc2 + b_fc2  [4096,1024] fp32  (128x64 tiles)
    gemm_mfma<2, 0, 4, 1, 2, 4><<<dim3(1024 / 64, M / 128), 256, 0, stream>>>(
        h2, wT_fc2, b_fc2, x1, out_x, M, 1024, 4096);
}

// Round 2
// 718.955 us; speedup vs baseline: 2.4691x; 1.0966x over previous
//
#include <hip/hip_runtime.h>
#include <cmath>

// Problem constants
#define BB 2
#define TT 2048
#define CC 1024
#define HH 16
#define DD 64

typedef unsigned short u16;
typedef __attribute__((ext_vector_type(8))) short bf16x8;   // 8 bf16 = 4 VGPRs
typedef __attribute__((ext_vector_type(4))) float f32x4;

__device__ __forceinline__ u16 f2bf(float f) {
    union { float f; unsigned u; } v; v.f = f;
    return (u16)((v.u + 0x7fff + ((v.u >> 16) & 1)) >> 16);   // RNE
}

__device__ __forceinline__ float bf2f(u16 h) {
    union { unsigned u; float f; } v; v.u = ((unsigned)h) << 16;
    return v.f;
}

__device__ __forceinline__ float gelu_exact(float v) {
    return 0.5f * v * (1.0f + erff(v * 0.70710678118654752440f));
}

__device__ __forceinline__ void glds16(const void* g, void* l) {
    __builtin_amdgcn_global_load_lds(
        (const __attribute__((address_space(1))) void*)g,
        (__attribute__((address_space(3))) void*)l, 16, 0, 0);
}

// ---------------------------------------------------------------------------
// Weight convert + transpose: W [K,N] fp32 -> WT [N,K] bf16. 64x64 tiles.
// ---------------------------------------------------------------------------
__global__ __launch_bounds__(256) void wcvt_kernel(const float* __restrict__ W,
                                                   u16* __restrict__ WT,
                                                   int K, int N) {
    __shared__ u16 t[64][65];
    const int n0 = blockIdx.x * 64, k0 = blockIdx.y * 64;
    const int tid = threadIdx.x;
    const int c = tid & 63;
#pragma unroll
    for (int it = 0; it < 16; ++it) {
        int r = it * 4 + (tid >> 6);
        t[c][r] = f2bf(W[(size_t)(k0 + r) * N + n0 + c]);
    }
    __syncthreads();
#pragma unroll
    for (int it = 0; it < 16; ++it) {
        int r = it * 4 + (tid >> 6);
        WT[(size_t)(n0 + r) * K + k0 + c] = t[r][c];
    }
}

// ---------------------------------------------------------------------------
// LayerNorm: fp32 in, bf16 out. One block per row of C=1024.
// ---------------------------------------------------------------------------
__global__ __launch_bounds__(256) void ln_kernel(const float* __restrict__ x,
                                                 const float* __restrict__ w,
                                                 const float* __restrict__ b,
                                                 u16* __restrict__ out) {
    const int row = blockIdx.x;
    const int tid = threadIdx.x;
    const float* xr = x + (size_t)row * CC;
    u16* orow = out + (size_t)row * CC;

    __shared__ float red[256];

    float v[4];
#pragma unroll
    for (int i = 0; i < 4; ++i) v[i] = xr[tid + i * 256];

    red[tid] = v[0] + v[1] + v[2] + v[3];
    __syncthreads();
    for (int off = 128; off > 0; off >>= 1) {
        if (tid < off) red[tid] += red[tid + off];
        __syncthreads();
    }
    const float mean = red[0] * (1.0f / CC);
    __syncthreads();

    float d[4], sq = 0.f;
#pragma unroll
    for (int i = 0; i < 4; ++i) { d[i] = v[i] - mean; sq += d[i] * d[i]; }
    red[tid] = sq;
    __syncthreads();
    for (int off = 128; off > 0; off >>= 1) {
        if (tid < off) red[tid] += red[tid + off];
        __syncthreads();
    }
    const float rstd = rsqrtf(red[0] * (1.0f / CC) + 1e-5f);

#pragma unroll
    for (int i = 0; i < 4; ++i) {
        int c = tid + i * 256;
        orow[c] = f2bf(d[i] * rstd * w[c] + b[c]);
    }
}

// ---------------------------------------------------------------------------
// bf16 MFMA GEMM (m97 structure): out[M,N] = epi(A[M,K] @ BT[N,K]^T + bias).
// ---------------------------------------------------------------------------
template <int EPI, int OUTBF, int WM, int WN, int FI, int FJ>
__global__ __launch_bounds__(256) void gemm_mfma(const u16* __restrict__ A,
                                                 const u16* __restrict__ BT,
                                                 const float* __restrict__ bias,
                                                 const float* __restrict__ res,
                                                 void* __restrict__ out,
                                                 int M, int N, int K) {
    constexpr int TM = WM * FI * 16;
    constexpr int TN = WN * FJ * 16;
    __shared__ u16 As[TM * 32];
    __shared__ u16 Bs[TN * 32];

    const int tid = threadIdx.x;
    const int lane = tid & 63;
    const int w = tid >> 6;                 // wave 0..3
    const int wr = w / WN, wc = w % WN;
    const int m16 = lane & 15;
    const int quad = lane >> 4;

    const int bm = blockIdx.y * TM;
    const int bn = blockIdx.x * TN;

    f32x4 acc[FI][FJ] = {};

    for (int k0 = 0; k0 < K; k0 += 32) {
#pragma unroll
        for (int it = 0; it < TM / 64; ++it) {
            int cb = w * (TM / 64) * 64 + it * 64;     // wave-uniform chunk base
            int q = cb + lane;
            glds16(&A[(size_t)(bm + (q >> 2)) * K + k0 + (q & 3) * 8], &As[cb * 8]);
        }
#pragma unroll
        for (int it = 0; it < TN / 64; ++it) {
            int cb = w * (TN / 64) * 64 + it * 64;
            int q = cb + lane;
            glds16(&BT[(size_t)(bn + (q >> 2)) * K + k0 + (q & 3) * 8], &Bs[cb * 8]);
        }
        __syncthreads();

        bf16x8 a[FI], b[FJ];
#pragma unroll
        for (int i = 0; i < FI; ++i)
            a[i] = *(const bf16x8*)&As[(wr * FI * 16 + 16 * i + m16) * 32 + quad * 8];
#pragma unroll
        for (int j = 0; j < FJ; ++j)
            b[j] = *(const bf16x8*)&Bs[(wc * FJ * 16 + 16 * j + m16) * 32 + quad * 8];
#pragma unroll
        for (int i = 0; i < FI; ++i)
#pragma unroll
            for (int j = 0; j < FJ; ++j)
                acc[i][j] = __builtin_amdgcn_mfma_f32_16x16x32_bf16(a[i], b[j], acc[i][j], 0, 0, 0);
        __syncthreads();
    }

#pragma unroll
    for (int i = 0; i < FI; ++i) {
        const int row = bm + wr * FI * 16 + 16 * i + quad * 4;
#pragma unroll
        for (int j = 0; j < FJ; ++j) {
            const int col = bn + wc * FJ * 16 + 16 * j + m16;
            const float bv = bias[col];
#pragma unroll
            for (int r = 0; r < 4; ++r) {
                float v = acc[i][j][r] + bv;
                if (EPI == 1) v = gelu_exact(v);
                if (EPI == 2) v += res[(size_t)(row + r) * N + col];
                if (OUTBF) ((u16*)out)[(size_t)(row + r) * N + col] = f2bf(v);
                else ((float*)out)[(size_t)(row + r) * N + col] = v;
            }
        }
    }
}

// ---------------------------------------------------------------------------
// qkv convert: per (b,h,tile) write K hi/lo bf16 and V^T bf16 as contiguous
// 8KB tiles with the XOR swizzle (col ^= (row&7)<<3, u16 units) pre-applied,
// so attn can stage them with raw global_load_lds (linear dest).
// grid = 1024 blocks: idx = (b*16+h)*32+st.
// ---------------------------------------------------------------------------
__global__ __launch_bounds__(256) void qkvcvt_kernel(const float* __restrict__ qkv,
                                                     u16* __restrict__ Khg,
                                                     u16* __restrict__ Klg,
                                                     u16* __restrict__ VTg) {
    const int idx = blockIdx.x;
    const int st = idx & 31;
    const int h = (idx >> 5) & 15;
    const int b = idx >> 9;
    const int tid = threadIdx.x;
    const size_t TC3 = 3 * CC;

    const float* kbase = qkv + (size_t)b * TT * TC3 + (size_t)st * 64 * TC3 + CC + h * DD;
    const float* vbase = kbase + CC;
    u16* kh = Khg + (size_t)idx * 4096;
    u16* kl = Klg + (size_t)idx * 4096;
    u16* vt = VTg + (size_t)idx * 4096;

    __shared__ u16 lvt[64][65];

#pragma unroll
    for (int it = 0; it < 4; ++it) {
        int e = tid + it * 256;
        int s = e >> 4, c4 = e & 15;
        float4 v = *reinterpret_cast<const float4*>(kbase + (size_t)s * TC3 + c4 * 4);
        float fv[4] = {v.x, v.y, v.z, v.w};
        u16 hh[4], ll[4];
#pragma unroll
        for (int i = 0; i < 4; ++i) {
            union { float f; unsigned u; } tb; tb.f = fv[i];
            hh[i] = (u16)(tb.u >> 16);
            ll[i] = f2bf(fv[i] - bf2f(hh[i]));
        }
        int col = (c4 * 4) ^ ((s & 7) << 3);
        *reinterpret_cast<ushort4*>(&kh[s * 64 + col]) = make_ushort4(hh[0], hh[1], hh[2], hh[3]);
        *reinterpret_cast<ushort4*>(&kl[s * 64 + col]) = make_ushort4(ll[0], ll[1], ll[2], ll[3]);
        // V -> LDS transposed (bf16)
        float4 vv = *reinterpret_cast<const float4*>(vbase + (size_t)s * TC3 + c4 * 4);
        lvt[c4 * 4 + 0][s] = f2bf(vv.x);
        lvt[c4 * 4 + 1][s] = f2bf(vv.y);
        lvt[c4 * 4 + 2][s] = f2bf(vv.z);
        lvt[c4 * 4 + 3][s] = f2bf(vv.w);
    }
    __syncthreads();
#pragma unroll
    for (int it = 0; it < 4; ++it) {
        int e = tid + it * 256;
        int d = e >> 4, s4 = (e & 15) * 4;
        ushort4 o = make_ushort4(lvt[d][s4], lvt[d][s4 + 1], lvt[d][s4 + 2], lvt[d][s4 + 3]);
        *reinterpret_cast<ushort4*>(&vt[d * 64 + (s4 ^ ((d & 7) << 3))]) = o;
    }
}

// ---------------------------------------------------------------------------
// MFMA two-pass causal attention, v2: pre-converted K/V tiles staged with
// global_load_lds (no in-loop conversion), Q in registers, P overlays dead
// K-hi LDS (wave-private rows => no extra barrier before PV).
// Barriers: pass A 2/tile, pass B 3/tile. LDS 48KB -> 3 blocks/CU.
// ---------------------------------------------------------------------------
__global__ __launch_bounds__(256) void attn_kernel(const float* __restrict__ qkv,
                                                   const u16* __restrict__ Khg,
                                                   const u16* __restrict__ Klg,
                                                   const u16* __restrict__ VTg,
                                                   float* __restrict__ attn_mean,
                                                   u16* __restrict__ attn_out) {
    const int lid = blockIdx.x;
    const int u = lid & 255;
    const int h = u & 15;
    const int ta = u >> 4;
    const int tt = (lid < 256) ? ta : 31 - ta;
    const int t0 = tt * 64;

    const int tid = threadIdx.x;
    const int lane = tid & 63;
    const int w = tid >> 6;                 // wave 0..3
    const int m16 = lane & 15;
    const int quad = lane >> 4;
    const size_t TC3 = 3 * CC;

    __shared__ u16 Ks[2][2][64][64];   // [batch][hi/lo]  32 KB
    __shared__ u16 VTs[2][64][64];     // [batch]         16 KB

    const int arow = w * 16 + m16;          // wave-private fragment row
    const int sw = (m16 & 7) << 3;          // read-side swizzle (u16 units)
    const int rbase = w * 16 + quad * 4;    // C/D row base within tile

    auto toff = [&](int b, int st) -> size_t {
        return ((size_t)((b * 16 + h) * 32 + st)) * 4096;
    };

    // stage one contiguous 8KB tile: 8 chunks of 1KB, wave w takes chunks 2w,2w+1
    auto stage_tile = [&](const u16* g, u16* l) {
        glds16(g + w * 1024 + lane * 8, l + w * 1024);
        glds16(g + w * 1024 + 512 + lane * 8, l + w * 1024 + 512);
    };

    // ---- Q fragments in registers (hi/lo, scaled 1/sqrt(D)) ----
    bf16x8 qh[2][2], ql[2][2];
#pragma unroll
    for (int b = 0; b < 2; ++b) {
        const float* qp = qkv + (size_t)b * TT * TC3 + (size_t)(t0 + arow) * TC3 + h * DD;
#pragma unroll
        for (int ks = 0; ks < 2; ++ks) {
            float4 v0 = *reinterpret_cast<const float4*>(qp + ks * 32 + quad * 8);
            float4 v1 = *reinterpret_cast<const float4*>(qp + ks * 32 + quad * 8 + 4);
            float f[8] = {v0.x, v0.y, v0.z, v0.w, v1.x, v1.y, v1.z, v1.w};
            union { bf16x8 v; u16 s[8]; } H, L;
#pragma unroll
            for (int i = 0; i < 8; ++i) {
                float fv = f[i] * 0.125f;
                union { float f; unsigned u; } tb; tb.f = fv;
                u16 hh = (u16)(tb.u >> 16);
                H.s[i] = hh;
                L.s[i] = f2bf(fv - bf2f(hh));
            }
            qh[b][ks] = H.v;
            ql[b][ks] = L.v;
        }
    }

    // S tile: acc += Qh*Kh + Ql*Kh + Qh*Kl (fp32-grade)
    auto compute_S = [&](const bf16x8 (&QH)[2], const bf16x8 (&QL)[2],
                         const u16 (*KH)[64], const u16 (*KL)[64],
                         f32x4 (&acc)[4], bool diag) {
#pragma unroll
        for (int ks = 0; ks < 2; ++ks) {
#pragma unroll
            for (int j = 0; j < 4; ++j) {
                const int co = (ks * 32 + quad * 8) ^ sw;
                bf16x8 bh = *(const bf16x8*)&KH[j * 16 + m16][co];
                bf16x8 bl = *(const bf16x8*)&KL[j * 16 + m16][co];
                acc[j] = __builtin_amdgcn_mfma_f32_16x16x32_bf16(QH[ks], bh, acc[j], 0, 0, 0);
                acc[j] = __builtin_amdgcn_mfma_f32_16x16x32_bf16(QL[ks], bh, acc[j], 0, 0, 0);
                acc[j] = __builtin_amdgcn_mfma_f32_16x16x32_bf16(QH[ks], bl, acc[j], 0, 0, 0);
            }
        }
        if (diag) {
#pragma unroll
            for (int j = 0; j < 4; ++j)
#pragma unroll
                for (int r = 0; r < 4; ++r)
                    if (j * 16 + m16 > rbase + r) acc[j][r] = -INFINITY;
        }
    };

    auto pv_acc = [&](f32x4 (&O)[4], const u16 (*Ps)[64], const u16 (*VT)[64]) {
#pragma unroll
        for (int ks = 0; ks < 2; ++ks) {
            const int co = (ks * 32 + quad * 8) ^ sw;
            bf16x8 a = *(const bf16x8*)&Ps[arow][co];
#pragma unroll
            for (int j = 0; j < 4; ++j) {
                bf16x8 bv = *(const bf16x8*)&VT[j * 16 + m16][co];
                O[j] = __builtin_amdgcn_mfma_f32_16x16x32_bf16(a, bv, O[j], 0, 0, 0);
            }
        }
    };

    // ---- Pass A: online row max m and denom l, fully in registers ----
    float m_r[2][4], l_r[2][4];
#pragma unroll
    for (int b = 0; b < 2; ++b)
#pragma unroll
        for (int r = 0; r < 4; ++r) { m_r[b][r] = -INFINITY; l_r[b][r] = 0.f; }

    for (int st = 0; st <= tt; ++st) {
        __syncthreads();
        stage_tile(Khg + toff(0, st), &Ks[0][0][0][0]);
        stage_tile(Klg + toff(0, st), &Ks[0][1][0][0]);
        stage_tile(Khg + toff(1, st), &Ks[1][0][0][0]);
        stage_tile(Klg + toff(1, st), &Ks[1][1][0][0]);
        __syncthreads();
        const bool diag = (st == tt);
#pragma unroll
        for (int b = 0; b < 2; ++b) {
            f32x4 acc[4] = {};
            compute_S(qh[b], ql[b], Ks[b][0], Ks[b][1], acc, diag);
#pragma unroll
            for (int r = 0; r < 4; ++r) {
                float t = fmaxf(fmaxf(acc[0][r], acc[1][r]), fmaxf(acc[2][r], acc[3][r]));
                t = fmaxf(t, __shfl_xor(t, 1));
                t = fmaxf(t, __shfl_xor(t, 2));
                t = fmaxf(t, __shfl_xor(t, 4));
                t = fmaxf(t, __shfl_xor(t, 8));
                const float mn = fmaxf(m_r[b][r], t);
                float s = __expf(acc[0][r] - mn) + __expf(acc[1][r] - mn) +
                          __expf(acc[2][r] - mn) + __expf(acc[3][r] - mn);
                s += __shfl_xor(s, 1);
                s += __shfl_xor(s, 2);
                s += __shfl_xor(s, 4);
                s += __shfl_xor(s, 8);
                l_r[b][r] = l_r[b][r] * __expf(m_r[b][r] - mn) + s;
                m_r[b][r] = mn;
            }
        }
    }
#pragma unroll
    for (int b = 0; b < 2; ++b)
#pragma unroll
        for (int r = 0; r < 4; ++r) l_r[b][r] = 1.0f / l_r[b][r];

    // ---- Pass B: recompute S, write attn_mean, PV via MFMA ----
    f32x4 O0[4] = {}, O1[4] = {};
    for (int st = 0; st <= tt; ++st) {
        const int s0 = st * 64;
        const bool diag = (st == tt);
        __syncthreads();
        stage_tile(Khg + toff(0, st), &Ks[0][0][0][0]);
        stage_tile(Klg + toff(0, st), &Ks[0][1][0][0]);
        stage_tile(Khg + toff(1, st), &Ks[1][0][0][0]);
        stage_tile(Klg + toff(1, st), &Ks[1][1][0][0]);
        stage_tile(VTg + toff(0, st), &VTs[0][0][0]);
        stage_tile(VTg + toff(1, st), &VTs[1][0][0]);
        __syncthreads();

        f32x4 a0[4] = {}, a1[4] = {};
        compute_S(qh[0], ql[0], Ks[0][0], Ks[0][1], a0, diag);
        compute_S(qh[1], ql[1], Ks[1][0], Ks[1][1], a1, diag);

        // P = exp(S - m) * (1/l), in place
#pragma unroll
        for (int j = 0; j < 4; ++j)
#pragma unroll
            for (int r = 0; r < 4; ++r) {
                a0[j][r] = __expf(a0[j][r] - m_r[0][r]) * l_r[0][r];
                a1[j][r] = __expf(a1[j][r] - m_r[1][r]) * l_r[1][r];
            }

        // attn_mean = 0.5*(P0+P1)
#pragma unroll
        for (int r = 0; r < 4; ++r) {
            float* mrow = attn_mean + ((size_t)h * TT + t0 + rbase + r) * TT + s0;
#pragma unroll
            for (int j = 0; j < 4; ++j)
                mrow[j * 16 + m16] = 0.5f * (a0[j][r] + a1[j][r]);
        }

        __syncthreads();   // all waves done reading Ks before P overlays K-hi

        // P (bf16, swizzled) overlays Ks[b][0]; rows are wave-private
#pragma unroll
        for (int r = 0; r < 4; ++r) {
            const int prow = rbase + r;
            const int psw = (prow & 7) << 3;
#pragma unroll
            for (int j = 0; j < 4; ++j) {
                Ks[0][0][prow][(j * 16 + m16) ^ psw] = f2bf(a0[j][r]);
                Ks[1][0][prow][(j * 16 + m16) ^ psw] = f2bf(a1[j][r]);
            }
        }
        pv_acc(O0, Ks[0][0], VTs[0]);
        pv_acc(O1, Ks[1][0], VTs[1]);
    }

    // ---- epilogue: att_o bf16 ----
#pragma unroll
    for (int r = 0; r < 4; ++r) {
        const int trow = t0 + rbase + r;
#pragma unroll
        for (int j = 0; j < 4; ++j) {
            attn_out[((size_t)0 * TT + trow) * CC + h * DD + j * 16 + m16] = f2bf(O0[j][r]);
            attn_out[((size_t)1 * TT + trow) * CC + h * DD + j * 16 + m16] = f2bf(O1[j][r]);
        }
    }

    // zero upper triangle of attn_mean rows owned by this block
    const int c0 = (tt + 1) * 64;
    const float4 z4 = make_float4(0.f, 0.f, 0.f, 0.f);
    for (int r = 0; r < 64; ++r) {
        float* row = attn_mean + ((size_t)h * TT + t0 + r) * TT;
        for (int c = c0 + tid * 4; c < TT; c += 1024)
            *reinterpret_cast<float4*>(row + c) = z4;
    }
}

// ---------------------------------------------------------------------------
extern "C" void kernel_launch(void* const* d_in, const int* in_sizes, int n_in,
                              void* d_out, int out_size, void* d_ws, size_t ws_size,
                              hipStream_t stream) {
    const float* x      = (const float*)d_in[0];
    const float* ln1_w  = (const float*)d_in[1];
    const float* ln1_b  = (const float*)d_in[2];
    const float* w_qkv  = (const float*)d_in[3];
    const float* b_qkv  = (const float*)d_in[4];
    const float* w_proj = (const float*)d_in[5];
    const float* b_proj = (const float*)d_in[6];
    const float* ln2_w  = (const float*)d_in[7];
    const float* ln2_b  = (const float*)d_in[8];
    const float* w_fc   = (const float*)d_in[9];
    const float* b_fc   = (const float*)d_in[10];
    const float* w_fc2  = (const float*)d_in[11];
    const float* b_fc2  = (const float*)d_in[12];

    float* out_x    = (float*)d_out;
    float* out_attn = out_x + (size_t)BB * TT * CC;

    char* wp = (char*)d_ws;
    u16* wT_qkv = (u16*)wp;  wp += (size_t)3072 * 1024 * 2;
    u16* wT_proj = (u16*)wp; wp += (size_t)1024 * 1024 * 2;
    u16* wT_fc  = (u16*)wp;  wp += (size_t)4096 * 1024 * 2;
    u16* wT_fc2 = (u16*)wp;  wp += (size_t)1024 * 4096 * 2;
    u16* h_ln   = (u16*)wp;  wp += (size_t)4096 * 1024 * 2;
    u16* att_o  = (u16*)wp;  wp += (size_t)4096 * 1024 * 2;
    u16* h2     = (u16*)wp;  wp += (size_t)4096 * 4096 * 2;
    float* qkv  = (float*)wp; wp += (size_t)4096 * 3072 * 4;
    float* x1   = (float*)wp; wp += (size_t)4096 * 1024 * 4;

    // attn staging arrays overlay h2 (dead until step 6): 3 x 8.39 MB = 25.2 MB
    u16* Khg = h2;
    u16* Klg = Khg + (size_t)1024 * 4096;
    u16* VTg = Klg + (size_t)1024 * 4096;

    const int M = BB * TT;   // 4096

    // weight convert+transpose (bf16, [N,K])
    wcvt_kernel<<<dim3(3072 / 64, 1024 / 64), 256, 0, stream>>>(w_qkv, wT_qkv, 1024, 3072);
    wcvt_kernel<<<dim3(1024 / 64, 1024 / 64), 256, 0, stream>>>(w_proj, wT_proj, 1024, 1024);
    wcvt_kernel<<<dim3(4096 / 64, 1024 / 64), 256, 0, stream>>>(w_fc, wT_fc, 1024, 4096);
    wcvt_kernel<<<dim3(1024 / 64, 4096 / 64), 256, 0, stream>>>(w_fc2, wT_fc2, 4096, 1024);

    // 1. LN1 -> bf16
    ln_kernel<<<M, 256, 0, stream>>>(x, ln1_w, ln1_b, h_ln);
    // 2. qkv = h_ln @ w_qkv + b_qkv  [4096,3072] fp32
    gemm_mfma<0, 0, 2, 2, 4, 4><<<dim3(3072 / 128, M / 128), 256, 0, stream>>>(
        h_ln, wT_qkv, b_qkv, nullptr, qkv, M, 3072, 1024);
    // 2b. pre-convert K hi/lo + V^T into swizzled bf16 tiles
    qkvcvt_kernel<<<1024, 256, 0, stream>>>(qkv, Khg, Klg, VTg);
    // 3. attention (bf16 tiles in, bf16 att_o out)
    attn_kernel<<<512, 256, 0, stream>>>(qkv, Khg, Klg, VTg, out_attn, att_o);
    // 4. x1 = x + att_o @ w_proj + b_proj  [4096,1024] fp32
    gemm_mfma<2, 0, 4, 1, 2, 4><<<dim3(1024 / 64, M / 128), 256, 0, stream>>>(
        att_o, wT_proj, b_proj, x, x1, M, 1024, 1024);
    // 5. LN2 -> bf16
    ln_kernel<<<M, 256, 0, stream>>>(x1, ln2_w, ln2_b, h_ln);
    // 6. h2 = gelu(h_ln @ w_fc + b_fc)  [4096,4096] bf16
    gemm_mfma<1, 1, 2, 2, 4, 4><<<dim3(4096 / 128, M / 128), 256, 0, stream>>>(
        h_ln, wT_fc, b_fc, nullptr, h2, M, 4096, 1024);
    // 7. out_x = x1 + h2 @ w_fc2 + b_fc2  [4096,1024] fp32
    gemm_mfma<2, 0, 4, 1, 2, 4><<<dim3(1024 / 64, M / 128), 256, 0, stream>>>(
        h2, wT_fc2, b_fc2, x1, out_x, M, 1024, 4096);
}